// Round 8
// baseline (98.856 us; speedup 1.0000x reference)
//
#include <hip/hip_runtime.h>
#include <hip/hip_bf16.h>
#include <stdint.h>

// Shapes fixed by the reference: N=8192, F_IN=128, F_OUT=64.
// DTYPE (settled rounds 2-7): inputs and output are f32. Internal bf16 MFMA,
// absmax 3.9e-3 vs threshold 1.49e-2. Harness fixed floor ~79 us (256 MB ws
// re-poison at ~41 us is timed); our kernels were ~17 us in round 7.
// Round 8: (1) k1 emits Wh in B-fragment-major layout whB so k2's B loads are
// single coalesced dwordx4 per lane; (2) k2 drops LDS/barriers entirely;
// (3) k1 W-gather via LDS-transposed bf16 W; (4) exp clamps removed (range
// proven: |logit| <= ~23).
typedef float f32x4 __attribute__((ext_vector_type(4)));
typedef short s16x8 __attribute__((ext_vector_type(8)));
typedef unsigned int u32x4 __attribute__((ext_vector_type(4)));

#define L2E 1.44269504088896f  // log2(e)

__device__ __forceinline__ unsigned short f2bf_rne(float f) {
    unsigned int u = __float_as_uint(f);
    u += 0x7fffu + ((u >> 16) & 1u);
    return (unsigned short)(u >> 16);
}

// ---------------------------------------------------------------------------
// k1: Wh = h@W (bf16 MFMA), f1L=(Wh@a1)*log2e, f2L=(Wh@a2)*log2e, and
//     whB = Wh^T in B-fragment-major layout:
//     whB[((jg*4 + b)*64 + lane)*8 + jj] = Wh[j = jg*32 + (lane>>4)*8 + jj]
//                                            [n = b*16 + (lane&15)]
// so k2's B-frag load is one contiguous 1 KB dwordx4 per wave.
// Grid: 128 x 256; block = 64 rows (= 2 jg groups).
// ---------------------------------------------------------------------------
__global__ __launch_bounds__(256) void k1_wh(
    const float* __restrict__ hf,
    const float* __restrict__ Wf,
    const float* __restrict__ af,
    unsigned short* __restrict__ whB,
    float* __restrict__ f1L,
    float* __restrict__ f2L)
{
    __shared__ __align__(16) unsigned short Wt[64][136];  // [n][k] bf16, pad->272B rows
    __shared__ __align__(16) unsigned short tb[64][72];   // [n][i_local], 144B rows
    const int tid  = threadIdx.x;
    const int lane = tid & 63;
    const int w    = tid >> 6;
    const int col  = lane & 15;
    const int quad = lane >> 4;
    const int i0   = blockIdx.x * 64;

    // stage W (128x64 f32 row-major) -> Wt[n][k] bf16 (transposed)
    #pragma unroll
    for (int it = 0; it < 8; ++it) {
        int fidx = tid + it * 256;        // f32x4 index 0..2047
        int k  = fidx >> 4;               // 0..127
        int n4 = (fidx & 15) << 2;        // 0..60
        f32x4 wv = *(const f32x4*)&Wf[k * 64 + n4];
        #pragma unroll
        for (int e = 0; e < 4; ++e)
            Wt[n4 + e][k] = f2bf_rne(wv[e]);
    }
    __syncthreads();

    f32x4 D[4];
    #pragma unroll
    for (int f = 0; f < 4; ++f) D[f] = (f32x4){0.f, 0.f, 0.f, 0.f};

    const int rowA = i0 + w * 16 + col;  // A operand: m = lane&15
    #pragma unroll
    for (int cs = 0; cs < 4; ++cs) {     // K = 128 in 4 steps of 32
        f32x4 h0 = *(const f32x4*)&hf[(size_t)rowA * 128 + cs * 32 + quad * 8];
        f32x4 h1 = *(const f32x4*)&hf[(size_t)rowA * 128 + cs * 32 + quad * 8 + 4];
        s16x8 A;
        #pragma unroll
        for (int jj = 0; jj < 4; ++jj) {
            A[jj]     = (short)f2bf_rne(h0[jj]);
            A[4 + jj] = (short)f2bf_rne(h1[jj]);
        }
        #pragma unroll
        for (int f = 0; f < 4; ++f) {    // B[k][n]: n = f*16+col, k = cs*32+quad*8+jj
            s16x8 B = *(const s16x8*)&Wt[f * 16 + col][cs * 32 + quad * 8];
            D[f] = __builtin_amdgcn_mfma_f32_16x16x32_bf16(A, B, D[f], 0, 0, 0);
        }
    }

    float a1v[4], a2v[4];
    #pragma unroll
    for (int f = 0; f < 4; ++f) {
        a1v[f] = af[f * 16 + col];
        a2v[f] = af[64 + f * 16 + col];
    }

    // D layout: row = quad*4 + r, col-of-Wh = f*16 + (lane&15)
    #pragma unroll
    for (int r = 0; r < 4; ++r) {
        float s1 = D[0][r]*a1v[0] + D[1][r]*a1v[1] + D[2][r]*a1v[2] + D[3][r]*a1v[3];
        float s2 = D[0][r]*a2v[0] + D[1][r]*a2v[1] + D[2][r]*a2v[2] + D[3][r]*a2v[3];
        #pragma unroll
        for (int d = 1; d < 16; d <<= 1) {  // reduce over the 16 cols
            s1 += __shfl_xor(s1, d, 64);
            s2 += __shfl_xor(s2, d, 64);
        }
        if (col == 0) {
            int i = i0 + w * 16 + quad * 4 + r;
            f1L[i] = s1 * L2E;
            f2L[i] = s2 * L2E;
        }
        #pragma unroll
        for (int f = 0; f < 4; ++f)
            tb[f * 16 + col][w * 16 + quad * 4 + r] = f2bf_rne(D[f][r]);
    }
    __syncthreads();

    // emit whB: 512 chunks of 16 B (2 jg groups x 4 b x 64 lanes)
    for (int idx = tid; idx < 512; idx += 256) {
        int lane_o = idx & 63;
        int bq     = (idx >> 6) & 3;
        int jg_l   = idx >> 8;                       // 0..1
        int col_o  = lane_o & 15, quad_o = lane_o >> 4;
        u32x4 v = *(const u32x4*)&tb[bq * 16 + col_o][jg_l * 32 + quad_o * 8];
        size_t off = (((size_t)((i0 >> 5) + jg_l) * 4 + bq) * 64 + lane_o) * 8;
        *(u32x4*)&whB[off] = v;
    }
}

// ---------------------------------------------------------------------------
// k2: fused attention partials, NO LDS / NO barriers. 64 rows x 1024-j chunk:
//     Apart[s][i][n] = sum_j p_ij * Wh[j][n],  rsumP[s][i] = sum_j p_ij
// p built in registers in MFMA A-fragment layout (exp2 in log2 domain);
// B-frags are single coalesced dwordx4 loads from whB; denominator via a 5th
// MFMA against an all-ones B (same bf16 p -> ratio rounding cancels).
// Grid: (128 row-tiles, 8 j-chunks) x 256 thr.
// ---------------------------------------------------------------------------
__global__ __launch_bounds__(256) void k2_attn(
    const unsigned short* __restrict__ whB,
    const float* __restrict__ f1L,
    const float* __restrict__ f2L,
    float* __restrict__ Apart,
    float* __restrict__ rsumP)
{
    const int tid  = threadIdx.x;
    const int lane = tid & 63;
    const int w    = tid >> 6;
    const int col  = lane & 15;
    const int quad = lane >> 4;
    const int i0   = blockIdx.x * 64;
    const int jb   = blockIdx.y * 1024;

    const float f1 = f1L[i0 + w * 16 + col];  // A-fragment row m = lane&15

    f32x4 D0 = (f32x4){0.f,0.f,0.f,0.f}, D1 = D0, D2 = D0, D3 = D0, Ds = D0;
    s16x8 ones;
    #pragma unroll
    for (int jj = 0; jj < 8; ++jj) ones[jj] = (short)0x3f80;  // bf16(1.0)

    // base of this chunk's fragment stream for this lane (ushort units)
    const unsigned short* bp = whB + ((size_t)(jb >> 5) * 256 + lane) * 8;

    #pragma unroll 2
    for (int jt = 0; jt < 32; ++jt) {      // 32 j's per iter
        const int jq = jb + jt * 32 + quad * 8;
        f32x4 fa = *(const f32x4*)&f2L[jq];
        f32x4 fb = *(const f32x4*)&f2L[jq + 4];
        const unsigned short* bb = bp + (size_t)jt * 2048;  // 4 frags x 512
        s16x8 B0 = *(const s16x8*)(bb);
        s16x8 B1 = *(const s16x8*)(bb + 512);
        s16x8 B2 = *(const s16x8*)(bb + 1024);
        s16x8 B3 = *(const s16x8*)(bb + 1536);
        unsigned int pb[8];
        #pragma unroll
        for (int e = 0; e < 4; ++e) {
            float u = f1 + fa[e];            // already *log2e
            u = fmaxf(u, 0.01f * u);         // LeakyReLU in log2 domain
            pb[e] = __float_as_uint(__builtin_amdgcn_exp2f(u));
            float v = f1 + fb[e];
            v = fmaxf(v, 0.01f * v);
            pb[4 + e] = __float_as_uint(__builtin_amdgcn_exp2f(v));
        }
        union { u32x4 u4; s16x8 s8; } Au;    // pack truncated bf16 pairs
        Au.u4[0] = __builtin_amdgcn_perm(pb[1], pb[0], 0x07060302u);
        Au.u4[1] = __builtin_amdgcn_perm(pb[3], pb[2], 0x07060302u);
        Au.u4[2] = __builtin_amdgcn_perm(pb[5], pb[4], 0x07060302u);
        Au.u4[3] = __builtin_amdgcn_perm(pb[7], pb[6], 0x07060302u);
        D0 = __builtin_amdgcn_mfma_f32_16x16x32_bf16(Au.s8, B0, D0, 0, 0, 0);
        D1 = __builtin_amdgcn_mfma_f32_16x16x32_bf16(Au.s8, B1, D1, 0, 0, 0);
        D2 = __builtin_amdgcn_mfma_f32_16x16x32_bf16(Au.s8, B2, D2, 0, 0, 0);
        D3 = __builtin_amdgcn_mfma_f32_16x16x32_bf16(Au.s8, B3, D3, 0, 0, 0);
        Ds = __builtin_amdgcn_mfma_f32_16x16x32_bf16(Au.s8, ones, Ds, 0, 0, 0);
    }

    float* Ap = Apart + (size_t)blockIdx.y * 524288;
    #pragma unroll
    for (int r = 0; r < 4; ++r) {   // D layout: row = quad*4+r, col n = 16*b + col
        int i = i0 + w * 16 + quad * 4 + r;
        Ap[(size_t)i * 64 +      col] = D0[r];
        Ap[(size_t)i * 64 + 16 + col] = D1[r];
        Ap[(size_t)i * 64 + 32 + col] = D2[r];
        Ap[(size_t)i * 64 + 48 + col] = D3[r];
        if (col == 0) rsumP[blockIdx.y * 8192 + i] = Ds[r];
    }
}

// ---------------------------------------------------------------------------
// k3: out(f32) = elu( sum_s Apart[s] / sum_s rsumP[s] ), vectorized x4.
// Grid: 512 x 256.
// ---------------------------------------------------------------------------
__global__ __launch_bounds__(256) void k3_combine(
    const float* __restrict__ Apart,
    const float* __restrict__ rsumP,
    float* __restrict__ out)
{
    int gid = blockIdx.x * 256 + threadIdx.x;  // 0 .. 131071
    int i  = gid >> 4;
    int c4 = (gid & 15) << 2;
    f32x4 num = (f32x4){0.f, 0.f, 0.f, 0.f};
    float den = 0.f;
    #pragma unroll
    for (int s = 0; s < 8; ++s) {
        num += *(const f32x4*)&Apart[(size_t)s * 524288 + (size_t)i * 64 + c4];
        den += rsumP[s * 8192 + i];
    }
    float rden = 1.f / den;
    f32x4 o;
    #pragma unroll
    for (int e = 0; e < 4; ++e) {
        float v = num[e] * rden;
        o[e] = v > 0.f ? v : (__builtin_amdgcn_exp2f(v * L2E) - 1.f);
    }
    *(f32x4*)&out[(size_t)i * 64 + c4] = o;
}

// ---------------------------------------------------------------------------
extern "C" void kernel_launch(void* const* d_in, const int* in_sizes, int n_in,
                              void* d_out, int out_size, void* d_ws, size_t ws_size,
                              hipStream_t stream) {
    const float* h = (const float*)d_in[0];  // 8192x128 f32
    const float* W = (const float*)d_in[1];  // 128x64 f32
    const float* a = (const float*)d_in[2];  // 128x1 f32
    float* out = (float*)d_out;              // 8192x64 f32

    char* ws = (char*)d_ws;
    unsigned short* whB = (unsigned short*)ws;        // 1 MB fragment-major Wh^T
    float* f1L   = (float*)(ws + 1048576);            // 32 KB
    float* f2L   = (float*)(ws + 1081344);            // 32 KB
    float* Apart = (float*)(ws + 1114112);            // 8 x 8192x64 f32 = 16 MB
    float* rsumP = (float*)(ws + 17891328);           // 8 x 8192 f32 = 256 KB
    // total ws ~18.1 MB (ws_size ~256 MB per fill counters)

    k1_wh<<<128, 256, 0, stream>>>(h, W, a, whB, f1L, f2L);
    k2_attn<<<dim3(128, 8), 256, 0, stream>>>(whB, f1L, f2L, Apart, rsumP);
    k3_combine<<<512, 256, 0, stream>>>(Apart, rsumP, out);
}